// Round 10
// baseline (655.575 us; speedup 1.0000x reference)
//
#include <hip/hip_runtime.h>
#include <math.h>

// Batch-major pipeline, LDS-staged activations (round 4).
// Receptive-field window: x 231..255 (25) -> h0 235..255 (21) ->
// y0 239..255 odd (9) -> h1 247..255 odd (5) -> y1@255 -> head. ~12.6 GFLOP.
// Layout: [feature_row][batch], batch stride-1 (R=4096), lane==batch.
// Each block stages its 64-batch activation slice in LDS (ci-chunked) so all
// 4 waves share one global read; weights in LDS read as wave-broadcast float4.

#define R     4096
#define CIN   30
#define LSEQ  256
#define C1    100
#define C2    200
#define KW    5
#define T0    231
#define WIN   25
#define NU0   21
#define NJ0   9
#define NT1   5

// ws rows (units of R floats = 16 KB each)
#define ROW_XT    0      // 750
#define ROW_H0T   750    // 2100 -> ends 2850
#define ROW_Y0T   2850   // 900  -> ends 3750
#define ROW_H1T   0      // 1000, aliases xT+h0T head (dead before k3)
#define ROW_FEAT  3750   // 200  -> ends 3950
#define ROW_HW1T  3950   // 40 rows (160000 floats) -> total 3990 rows = 65.4 MB

// ---------------- K0: transpose x window -> xT[(ci*25+u)][b] ----------------
__global__ __launch_bounds__(256) void k_tr(const float* __restrict__ x,
                                            float* __restrict__ xT) {
  const int l = threadIdx.x & 63, wv = threadIdx.x >> 6;
  const int b = blockIdx.x * 64 + l;
  const float* xb = x + (size_t)b * (CIN * LSEQ) + T0;
  for (int r2 = wv; r2 < 150; r2 += 4) {
    const int r = blockIdx.y * 150 + r2;
    const int ci = r / WIN, u = r - ci * WIN;
    xT[(size_t)r * R + b] = xb[ci * LSEQ + u];
  }
}

// ------------- K0b: transpose hw1 (H,C1,C2) -> hw1T (H,C2,C1) ---------------
__global__ __launch_bounds__(256) void k_trW(const float* __restrict__ hw1,
                                             float* __restrict__ hw1T) {
  const int idx = blockIdx.x * 256 + threadIdx.x;
  if (idx < 8 * C1 * C2) {
    const int h = idx / (C1 * C2);
    const int r = idx - h * (C1 * C2);
    const int o = r / C2, d = r - o * C2;
    hw1T[h * (C1 * C2) + d * C1 + o] = hw1[idx];
  }
}

// ------------- K1: h0T[(c*21+u)][b] = relu(conv1_0), staged x ---------------
#define CH1 10
__global__ __launch_bounds__(256) void k1(const float* __restrict__ xT,
                                          const float* __restrict__ w1,
                                          const float* __restrict__ b1,
                                          float* __restrict__ h0T) {
  __shared__ float wT[CIN * KW * 16];   // [kk][cl], 9.6 KB
  __shared__ float xs[CH1 * WIN * 64];  // 64 KB
  const int tid = threadIdx.x;
  const int ctile = blockIdx.y * 16;
  for (int idx = tid; idx < CIN * KW * 16; idx += 256) {
    const int cl = idx / (CIN * KW), kk = idx - cl * (CIN * KW);
    const int c = ctile + cl;
    wT[kk * 16 + cl] = (c < C1) ? w1[c * (CIN * KW) + kk] : 0.f;
  }
  const int l = tid & 63, wv = tid >> 6;
  const int b = blockIdx.x * 64 + l;
  const int cb = ctile + wv * 4;
  float acc[4][NU0];
#pragma unroll
  for (int m = 0; m < 4; ++m) {
    const float bias = (cb + m < C1) ? b1[cb + m] : 0.f;
#pragma unroll
    for (int u = 0; u < NU0; ++u) acc[m][u] = bias;
  }
  for (int ch = 0; ch < 3; ++ch) {
    __syncthreads();
    for (int idx = tid; idx < CH1 * WIN * 64; idx += 256) {
      const int rr = idx >> 6, bb = idx & 63;
      xs[idx] = xT[(size_t)(ch * (CH1 * WIN) + rr) * R + blockIdx.x * 64 + bb];
    }
    __syncthreads();
    for (int cil = 0; cil < CH1; ++cil) {
      const int ci = ch * CH1 + cil;
      float xr[WIN];
#pragma unroll
      for (int u = 0; u < WIN; ++u) xr[u] = xs[(cil * WIN + u) * 64 + l];
#pragma unroll
      for (int k = 0; k < KW; ++k) {
        const float4 w = *reinterpret_cast<const float4*>(&wT[(ci * KW + k) * 16 + wv * 4]);
#pragma unroll
        for (int u = 0; u < NU0; ++u) {
          acc[0][u] = fmaf(xr[u + k], w.x, acc[0][u]);
          acc[1][u] = fmaf(xr[u + k], w.y, acc[1][u]);
          acc[2][u] = fmaf(xr[u + k], w.z, acc[2][u]);
          acc[3][u] = fmaf(xr[u + k], w.w, acc[3][u]);
        }
      }
    }
  }
#pragma unroll
  for (int m = 0; m < 4; ++m) {
    const int c = cb + m;
    if (c < C1) {
#pragma unroll
      for (int u = 0; u < NU0; ++u)
        h0T[(size_t)(c * NU0 + u) * R + b] = fmaxf(acc[m][u], 0.f);
    }
  }
}

// --- K2: y0T = relu(relu(conv2_0) + wd_0*x + bd_0), staged h0, K=500+30 -----
#define CH2 8
__global__ __launch_bounds__(256) void k2(const float* __restrict__ xT,
                                          const float* __restrict__ h0T,
                                          const float* __restrict__ w2,
                                          const float* __restrict__ b2,
                                          const float* __restrict__ wd,
                                          const float* __restrict__ bd,
                                          float* __restrict__ y0T) {
  __shared__ float wT[C1 * KW * 16];   // 32 KB
  __shared__ float wdT[CIN * 16];      // 1.9 KB
  __shared__ float hs[CH2 * NU0 * 64]; // 43 KB
  const int tid = threadIdx.x;
  const int ctile = blockIdx.y * 16;
  for (int idx = tid; idx < C1 * KW * 16; idx += 256) {
    const int cl = idx / (C1 * KW), kk = idx - cl * (C1 * KW);
    const int c = ctile + cl;
    wT[kk * 16 + cl] = (c < C1) ? w2[c * (C1 * KW) + kk] : 0.f;
  }
  for (int idx = tid; idx < CIN * 16; idx += 256) {
    const int cl = idx / CIN, ci = idx - cl * CIN;
    const int c = ctile + cl;
    wdT[ci * 16 + cl] = (c < C1) ? wd[c * CIN + ci] : 0.f;
  }
  const int l = tid & 63, wv = tid >> 6;
  const int b = blockIdx.x * 64 + l;
  const int cb = ctile + wv * 4;
  float acc[4][NJ0], rac[4][NJ0];
#pragma unroll
  for (int m = 0; m < 4; ++m) {
    const float bias = (cb + m < C1) ? b2[cb + m] : 0.f;
    const float bres = (cb + m < C1) ? bd[cb + m] : 0.f;
#pragma unroll
    for (int j = 0; j < NJ0; ++j) { acc[m][j] = bias; rac[m][j] = bres; }
  }
  __syncthreads();  // wT/wdT ready
  // residual (direct coalesced reads; 270/thread, L2-hot)
  for (int ci = 0; ci < CIN; ++ci) {
    float xr[NJ0];
    const float* xp = xT + (size_t)(ci * WIN + 8) * R + b;
#pragma unroll
    for (int j = 0; j < NJ0; ++j) xr[j] = xp[(size_t)(2 * j) * R];
    const float4 w = *reinterpret_cast<const float4*>(&wdT[ci * 16 + wv * 4]);
#pragma unroll
    for (int j = 0; j < NJ0; ++j) {
      rac[0][j] = fmaf(xr[j], w.x, rac[0][j]);
      rac[1][j] = fmaf(xr[j], w.y, rac[1][j]);
      rac[2][j] = fmaf(xr[j], w.z, rac[2][j]);
      rac[3][j] = fmaf(xr[j], w.w, rac[3][j]);
    }
  }
  for (int c8 = 0; c8 < 13; ++c8) {
    const int nci = min(CH2, C1 - c8 * CH2);
    __syncthreads();
    for (int idx = tid; idx < nci * NU0 * 64; idx += 256) {
      const int rr = idx >> 6, bb = idx & 63;
      hs[idx] = h0T[(size_t)(c8 * CH2 * NU0 + rr) * R + blockIdx.x * 64 + bb];
    }
    __syncthreads();
    for (int cil = 0; cil < nci; ++cil) {
      const int ci = c8 * CH2 + cil;
      float hr[NU0];
#pragma unroll
      for (int u = 0; u < NU0; ++u) hr[u] = hs[(cil * NU0 + u) * 64 + l];
#pragma unroll
      for (int k = 0; k < KW; ++k) {
        const float4 w = *reinterpret_cast<const float4*>(&wT[(ci * KW + k) * 16 + wv * 4]);
#pragma unroll
        for (int j = 0; j < NJ0; ++j) {
          acc[0][j] = fmaf(hr[2 * j + k], w.x, acc[0][j]);
          acc[1][j] = fmaf(hr[2 * j + k], w.y, acc[1][j]);
          acc[2][j] = fmaf(hr[2 * j + k], w.z, acc[2][j]);
          acc[3][j] = fmaf(hr[2 * j + k], w.w, acc[3][j]);
        }
      }
    }
  }
#pragma unroll
  for (int m = 0; m < 4; ++m) {
    const int c = cb + m;
    if (c < C1) {
#pragma unroll
      for (int j = 0; j < NJ0; ++j)
        y0T[(size_t)(c * NJ0 + j) * R + b] =
            fmaxf(fmaxf(acc[m][j], 0.f) + rac[m][j], 0.f);
    }
  }
}

// -------- K3: h1T = relu(conv1_1 dil2), staged y0, K=(100ci,5k) -------------
#define CH3 16
__global__ __launch_bounds__(256) void k3(const float* __restrict__ y0T,
                                          const float* __restrict__ w1,
                                          const float* __restrict__ b1,
                                          float* __restrict__ h1T) {
  __shared__ float wT[C1 * KW * 16];    // 32 KB
  __shared__ float ys[CH3 * NJ0 * 64];  // 36.9 KB
  const int tid = threadIdx.x;
  const int ctile = blockIdx.y * 16;
  for (int idx = tid; idx < C1 * KW * 16; idx += 256) {
    const int cl = idx / (C1 * KW), kk = idx - cl * (C1 * KW);
    const int c = ctile + cl;
    wT[kk * 16 + cl] = (c < C2) ? w1[c * (C1 * KW) + kk] : 0.f;
  }
  const int l = tid & 63, wv = tid >> 6;
  const int b = blockIdx.x * 64 + l;
  const int cb = ctile + wv * 4;
  float acc[4][NT1];
#pragma unroll
  for (int m = 0; m < 4; ++m) {
    const float bias = (cb + m < C2) ? b1[cb + m] : 0.f;
#pragma unroll
    for (int t = 0; t < NT1; ++t) acc[m][t] = bias;
  }
  for (int c16 = 0; c16 < 7; ++c16) {
    const int nci = min(CH3, C1 - c16 * CH3);
    __syncthreads();
    for (int idx = tid; idx < nci * NJ0 * 64; idx += 256) {
      const int rr = idx >> 6, bb = idx & 63;
      ys[idx] = y0T[(size_t)(c16 * CH3 * NJ0 + rr) * R + blockIdx.x * 64 + bb];
    }
    __syncthreads();
    for (int cil = 0; cil < nci; ++cil) {
      const int ci = c16 * CH3 + cil;
      float yr[NJ0];
#pragma unroll
      for (int u = 0; u < NJ0; ++u) yr[u] = ys[(cil * NJ0 + u) * 64 + l];
#pragma unroll
      for (int k = 0; k < KW; ++k) {
        const float4 w = *reinterpret_cast<const float4*>(&wT[(ci * KW + k) * 16 + wv * 4]);
#pragma unroll
        for (int t = 0; t < NT1; ++t) {
          acc[0][t] = fmaf(yr[t + k], w.x, acc[0][t]);
          acc[1][t] = fmaf(yr[t + k], w.y, acc[1][t]);
          acc[2][t] = fmaf(yr[t + k], w.z, acc[2][t]);
          acc[3][t] = fmaf(yr[t + k], w.w, acc[3][t]);
        }
      }
    }
  }
#pragma unroll
  for (int m = 0; m < 4; ++m) {
    const int c = cb + m;
    if (c < C2) {
#pragma unroll
      for (int t = 0; t < NT1; ++t)
        h1T[(size_t)(c * NT1 + t) * R + b] = fmaxf(acc[m][t], 0.f);
    }
  }
}

// ------ K4a: featT[c][b] = relu(relu(conv2_1@255) + res), staged ------------
#define KC4 100
__global__ __launch_bounds__(256) void k4a(const float* __restrict__ h1T,
                                           const float* __restrict__ y0T,
                                           const float* __restrict__ w2,
                                           const float* __restrict__ b2,
                                           const float* __restrict__ wd,
                                           const float* __restrict__ bd,
                                           float* __restrict__ featT) {
  __shared__ float as[KC4 * 64];  // 25.6 KB
  __shared__ float wc[KC4 * 32];  // 12.8 KB
  const int tid = threadIdx.x;
  const int ctile = blockIdx.y * 32;
  const int l = tid & 63, wv = tid >> 6;
  const int b = blockIdx.x * 64 + l;
  const int c0 = ctile + wv * 8;
  float acc[8], rs[8];
#pragma unroll
  for (int m = 0; m < 8; ++m) {
    const int c = c0 + m;
    acc[m] = (c < C2) ? b2[c] : 0.f;
    rs[m] = (c < C2) ? bd[c] : 0.f;
  }
  for (int ph = 0; ph < 10; ++ph) {
    __syncthreads();
    for (int idx = tid; idx < KC4 * 64; idx += 256) {
      const int rr = idx >> 6, bb = idx & 63;
      as[idx] = h1T[(size_t)(ph * KC4 + rr) * R + blockIdx.x * 64 + bb];
    }
    for (int idx = tid; idx < KC4 * 32; idx += 256) {
      const int cl = idx / KC4, kk = idx - cl * KC4;
      const int c = ctile + cl;
      wc[kk * 32 + cl] = (c < C2) ? w2[(size_t)c * (C2 * KW) + ph * KC4 + kk] : 0.f;
    }
    __syncthreads();
    for (int kkl = 0; kkl < KC4; ++kkl) {
      const float a = as[kkl * 64 + l];
      const float4 w0 = *reinterpret_cast<const float4*>(&wc[kkl * 32 + wv * 8]);
      const float4 w1_ = *reinterpret_cast<const float4*>(&wc[kkl * 32 + wv * 8 + 4]);
      acc[0] = fmaf(a, w0.x, acc[0]); acc[1] = fmaf(a, w0.y, acc[1]);
      acc[2] = fmaf(a, w0.z, acc[2]); acc[3] = fmaf(a, w0.w, acc[3]);
      acc[4] = fmaf(a, w1_.x, acc[4]); acc[5] = fmaf(a, w1_.y, acc[5]);
      acc[6] = fmaf(a, w1_.z, acc[6]); acc[7] = fmaf(a, w1_.w, acc[7]);
    }
  }
  // residual: y0 @ t=255 (row ci*9+8), wd_1
  __syncthreads();
  for (int idx = tid; idx < C1 * 64; idx += 256) {
    const int rr = idx >> 6, bb = idx & 63;
    as[idx] = y0T[(size_t)(rr * NJ0 + 8) * R + blockIdx.x * 64 + bb];
  }
  for (int idx = tid; idx < C1 * 32; idx += 256) {
    const int cl = idx / C1, ci = idx - cl * C1;
    const int c = ctile + cl;
    wc[ci * 32 + cl] = (c < C2) ? wd[c * C1 + ci] : 0.f;
  }
  __syncthreads();
  for (int ci = 0; ci < C1; ++ci) {
    const float a = as[ci * 64 + l];
    const float4 w0 = *reinterpret_cast<const float4*>(&wc[ci * 32 + wv * 8]);
    const float4 w1_ = *reinterpret_cast<const float4*>(&wc[ci * 32 + wv * 8 + 4]);
    rs[0] = fmaf(a, w0.x, rs[0]); rs[1] = fmaf(a, w0.y, rs[1]);
    rs[2] = fmaf(a, w0.z, rs[2]); rs[3] = fmaf(a, w0.w, rs[3]);
    rs[4] = fmaf(a, w1_.x, rs[4]); rs[5] = fmaf(a, w1_.y, rs[5]);
    rs[6] = fmaf(a, w1_.z, rs[6]); rs[7] = fmaf(a, w1_.w, rs[7]);
  }
#pragma unroll
  for (int m = 0; m < 8; ++m) {
    const int c = c0 + m;
    if (c < C2)
      featT[(size_t)c * R + b] = fmaxf(fmaxf(acc[m], 0.f) + rs[m], 0.f);
  }
}

// -------- K4b: per-batch head, transposed W1 (coalesced), wave=item ---------
__global__ __launch_bounds__(256) void k4b(const float* __restrict__ featT,
                                           const int* __restrict__ labels,
                                           const float* __restrict__ hw1T,
                                           const float* __restrict__ hb1,
                                           const float* __restrict__ hw2,
                                           const float* __restrict__ hb2,
                                           float* __restrict__ out) {
  __shared__ float fs[4][C2];
  const int tid = threadIdx.x;
  const int b0 = blockIdx.x * 4;
  for (int idx = tid; idx < 4 * C2; idx += 256) {
    const int c = idx >> 2, bi = idx & 3;
    fs[bi][c] = featT[(size_t)c * R + b0 + bi];
  }
  __syncthreads();
  const int l = tid & 63, wv = tid >> 6;
  const int b = b0 + wv;
  const int task = labels[b];
  const float* Wt = hw1T + (size_t)task * (C1 * C2);  // [d][o]
  const float* fp = fs[wv];
  float a0 = hb1[task * C1 + l];
  float a1 = (l < C1 - 64) ? hb1[task * C1 + 64 + l] : 0.f;
  for (int d = 0; d < C2; ++d) {
    const float fd = fp[d];
    const float* row = Wt + d * C1;
    a0 = fmaf(fd, row[l], a0);
    if (l < C1 - 64) a1 = fmaf(fd, row[64 + l], a1);
  }
  float p = tanhf(a0) * hw2[task * C1 + l];
  if (l < C1 - 64) p = fmaf(tanhf(a1), hw2[task * C1 + 64 + l], p);
#pragma unroll
  for (int off = 32; off > 0; off >>= 1) p += __shfl_down(p, off, 64);
  if (l == 0) out[b] = p + hb2[task];
}

extern "C" void kernel_launch(void* const* d_in, const int* in_sizes, int n_in,
                              void* d_out, int out_size, void* d_ws, size_t ws_size,
                              hipStream_t stream) {
  const float* x    = (const float*)d_in[0];
  const int* labels = (const int*)d_in[1];
  const float* w1_0 = (const float*)d_in[2];
  const float* b1_0 = (const float*)d_in[3];
  const float* w2_0 = (const float*)d_in[4];
  const float* b2_0 = (const float*)d_in[5];
  const float* wd_0 = (const float*)d_in[6];
  const float* bd_0 = (const float*)d_in[7];
  const float* w1_1 = (const float*)d_in[8];
  const float* b1_1 = (const float*)d_in[9];
  const float* w2_1 = (const float*)d_in[10];
  const float* b2_1 = (const float*)d_in[11];
  const float* wd_1 = (const float*)d_in[12];
  const float* bd_1 = (const float*)d_in[13];
  const float* hw1  = (const float*)d_in[14];
  const float* hb1  = (const float*)d_in[15];
  const float* hw2  = (const float*)d_in[16];
  const float* hb2  = (const float*)d_in[17];
  float* out = (float*)d_out;

  float* ws    = (float*)d_ws;
  float* xT    = ws + (size_t)ROW_XT * R;
  float* h0T   = ws + (size_t)ROW_H0T * R;
  float* y0T   = ws + (size_t)ROW_Y0T * R;
  float* h1T   = ws + (size_t)ROW_H1T * R;   // aliases xT/h0T (dead by k3)
  float* featT = ws + (size_t)ROW_FEAT * R;
  float* hw1T  = ws + (size_t)ROW_HW1T * R;

  hipLaunchKernelGGL(k_trW, dim3(625), dim3(256), 0, stream, hw1, hw1T);
  hipLaunchKernelGGL(k_tr, dim3(64, 5), dim3(256), 0, stream, x, xT);
  hipLaunchKernelGGL(k1, dim3(64, 7), dim3(256), 0, stream, xT, w1_0, b1_0, h0T);
  hipLaunchKernelGGL(k2, dim3(64, 7), dim3(256), 0, stream, xT, h0T, w2_0, b2_0, wd_0, bd_0, y0T);
  hipLaunchKernelGGL(k3, dim3(64, 13), dim3(256), 0, stream, y0T, w1_1, b1_1, h1T);
  hipLaunchKernelGGL(k4a, dim3(64, 7), dim3(256), 0, stream, h1T, y0T, w2_1, b2_1, wd_1, bd_1, featT);
  hipLaunchKernelGGL(k4b, dim3(1024), dim3(256), 0, stream, featT, labels,
                     hw1T, hb1, hw2, hb2, out);
}

// Round 11
// 618.541 us; speedup vs baseline: 1.0599x; 1.0599x over previous
//
#include <hip/hip_runtime.h>
#include <math.h>

// Round 11: no-LDS conv kernels. Weights via wave-uniform (readfirstlane ->
// s_load) reads from pre-transposed [k][c] layouts; acts via coalesced global
// reads (lane==batch); XCD-swizzled linear grids (id = ct*64 + bblk so all
// channel-tiles of a batch-slice share one XCD's L2). Receptive-field window:
// x 231..255 -> h0(21) -> y0(9) -> h1(5) -> y1@255 -> head. ~12.6 GFLOP.

#define R     4096
#define CIN   30
#define LSEQ  256
#define C1    100
#define C2    200
#define KW    5
#define T0    231
#define WIN   25
#define NU0   21
#define NJ0   9
#define NT1   5

// ---- workspace layout (float offsets). Total 3884 rows x 4096 = 63.6 MB ----
#define OFF_HW1T  0          // 160000
#define OFF_WT10  160000     // 15000   w1_0T [150][100]
#define OFF_WT20  175000     // 50000   w2_0T [500][100]
#define OFF_WDT0  225000     // 3000    wd_0T [30][100]
#define OFF_WT11  228000     // 100000  w1_1T [500][200]
#define OFF_WT21  328000     // 200000  w2_1T [1000][200]
#define OFF_WDT1  528000     // 20000   wd_1T [100][200]
#define ROW_XT    134        // 750 rows (xT)
#define ROW_H0T   884        // 2100 rows
#define ROW_Y0T   2984       // 900 rows -> ends 3884
#define ROW_H1T   134        // 1000 rows, aliases xT+h0T head (dead by k3)
#define ROW_FEAT  1134       // 200 rows, inside dead h0T (k4a runs after k2)

// ------ K_prep: fused transposes (dst-linear; sources are small + cached) ---
#define NPREP 548000
__global__ __launch_bounds__(256) void k_prep(
    const float* __restrict__ hw1, const float* __restrict__ w1_0,
    const float* __restrict__ w2_0, const float* __restrict__ wd_0,
    const float* __restrict__ w1_1, const float* __restrict__ w2_1,
    const float* __restrict__ wd_1, float* __restrict__ ws) {
  int idx = blockIdx.x * 256 + threadIdx.x;
  if (idx >= NPREP) return;
  if (idx < 160000) {  // hw1T[h][d][o] = hw1[h][o][d]
    const int h = idx / 20000, r = idx - h * 20000;
    const int d = r / C1, o = r - d * C1;
    ws[OFF_HW1T + idx] = hw1[h * 20000 + o * C2 + d];
  } else if (idx < 175000) {  // wT10[kk][c]
    const int r = idx - 160000, kk = r / C1, c = r - kk * C1;
    ws[idx] = w1_0[c * (CIN * KW) + kk];
  } else if (idx < 225000) {  // wT20[kk][c]
    const int r = idx - 175000, kk = r / C1, c = r - kk * C1;
    ws[idx] = w2_0[c * (C1 * KW) + kk];
  } else if (idx < 228000) {  // wdT0[ci][c]
    const int r = idx - 225000, ci = r / C1, c = r - ci * C1;
    ws[idx] = wd_0[c * CIN + ci];
  } else if (idx < 328000) {  // wT11[kk][c]
    const int r = idx - 228000, kk = r / C2, c = r - kk * C2;
    ws[idx] = w1_1[c * (C1 * KW) + kk];
  } else if (idx < 528000) {  // wT21[kk][c]
    const int r = idx - 328000, kk = r / C2, c = r - kk * C2;
    ws[idx] = w2_1[(size_t)c * (C2 * KW) + kk];
  } else {  // wdT1[ci][c]
    const int r = idx - 528000, ci = r / C2, c = r - ci * C2;
    ws[idx] = wd_1[c * C1 + ci];
  }
}

// ---------------- K_tr: transpose x window -> xT[(ci*25+u)][b] --------------
__global__ __launch_bounds__(256) void k_tr(const float* __restrict__ x,
                                            float* __restrict__ xT) {
  const int l = threadIdx.x & 63, wv = threadIdx.x >> 6;
  const int b = blockIdx.x * 64 + l;
  const float* xb = x + (size_t)b * (CIN * LSEQ) + T0;
  for (int r2 = wv; r2 < 150; r2 += 4) {
    const int r = blockIdx.y * 150 + r2;
    const int ci = r / WIN, u = r - ci * WIN;
    xT[(size_t)r * R + b] = xb[ci * LSEQ + u];
  }
}

// ------------ K1: h0T = relu(conv1_0). 2 ch/thread, scalar weights ----------
__global__ __launch_bounds__(256) void k1(const float* __restrict__ xT,
                                          const float* __restrict__ wT10,
                                          const float* __restrict__ b1,
                                          float* __restrict__ h0T) {
  const int id = blockIdx.x;
  const int bblk = id & 63, ct = id >> 6;  // 13 ctiles of 8 ch
  const int tid = threadIdx.x;
  const int l = tid & 63, wv = tid >> 6;
  const int b = bblk * 64 + l;
  int c0 = ct * 8 + __builtin_amdgcn_readfirstlane(wv) * 2;
  c0 = (c0 > C1 - 2) ? C1 - 2 : c0;  // clamp (dup writes identical)
  float acc0[NU0], acc1[NU0];
  const float bi0 = b1[c0], bi1 = b1[c0 + 1];
#pragma unroll
  for (int u = 0; u < NU0; ++u) { acc0[u] = bi0; acc1[u] = bi1; }
  for (int ci = 0; ci < CIN; ++ci) {
    float xr[WIN];
#pragma unroll
    for (int u = 0; u < WIN; ++u) xr[u] = xT[(size_t)(ci * WIN + u) * R + b];
#pragma unroll
    for (int k = 0; k < KW; ++k) {
      const float* wr = wT10 + (ci * KW + k) * C1 + c0;  // uniform -> s_load
      const float w0 = wr[0], w1v = wr[1];
#pragma unroll
      for (int u = 0; u < NU0; ++u) {
        acc0[u] = fmaf(xr[u + k], w0, acc0[u]);
        acc1[u] = fmaf(xr[u + k], w1v, acc1[u]);
      }
    }
  }
#pragma unroll
  for (int u = 0; u < NU0; ++u) {
    h0T[(size_t)(c0 * NU0 + u) * R + b] = fmaxf(acc0[u], 0.f);
    h0T[(size_t)((c0 + 1) * NU0 + u) * R + b] = fmaxf(acc1[u], 0.f);
  }
}

// --- K2: y0T = relu(relu(conv2_0) + wd_0*x + bd_0). 2 ch/thread, scalar w ---
__global__ __launch_bounds__(256) void k2(const float* __restrict__ xT,
                                          const float* __restrict__ h0T,
                                          const float* __restrict__ wT20,
                                          const float* __restrict__ b2,
                                          const float* __restrict__ wdT0,
                                          const float* __restrict__ bd,
                                          float* __restrict__ y0T) {
  const int id = blockIdx.x;
  const int bblk = id & 63, ct = id >> 6;
  const int tid = threadIdx.x;
  const int l = tid & 63, wv = tid >> 6;
  const int b = bblk * 64 + l;
  int c0 = ct * 8 + __builtin_amdgcn_readfirstlane(wv) * 2;
  c0 = (c0 > C1 - 2) ? C1 - 2 : c0;
  float acc0[NJ0], acc1[NJ0], rac0[NJ0], rac1[NJ0];
  {
    const float bA = b2[c0], bB = b2[c0 + 1];
    const float dA = bd[c0], dB = bd[c0 + 1];
#pragma unroll
    for (int j = 0; j < NJ0; ++j) { acc0[j] = bA; acc1[j] = bB; rac0[j] = dA; rac1[j] = dB; }
  }
  // residual from x (t = 239+2j window rows ci*25+8+2j)
  for (int ci = 0; ci < CIN; ++ci) {
    float xr[NJ0];
#pragma unroll
    for (int j = 0; j < NJ0; ++j) xr[j] = xT[(size_t)(ci * WIN + 8 + 2 * j) * R + b];
    const float* wr = wdT0 + ci * C1 + c0;
    const float w0 = wr[0], w1v = wr[1];
#pragma unroll
    for (int j = 0; j < NJ0; ++j) {
      rac0[j] = fmaf(xr[j], w0, rac0[j]);
      rac1[j] = fmaf(xr[j], w1v, rac1[j]);
    }
  }
  for (int ci = 0; ci < C1; ++ci) {
    float hr[NU0];
#pragma unroll
    for (int u = 0; u < NU0; ++u) hr[u] = h0T[(size_t)(ci * NU0 + u) * R + b];
#pragma unroll
    for (int k = 0; k < KW; ++k) {
      const float* wr = wT20 + (ci * KW + k) * C1 + c0;
      const float w0 = wr[0], w1v = wr[1];
#pragma unroll
      for (int j = 0; j < NJ0; ++j) {
        acc0[j] = fmaf(hr[2 * j + k], w0, acc0[j]);
        acc1[j] = fmaf(hr[2 * j + k], w1v, acc1[j]);
      }
    }
  }
#pragma unroll
  for (int j = 0; j < NJ0; ++j) {
    y0T[(size_t)(c0 * NJ0 + j) * R + b] = fmaxf(fmaxf(acc0[j], 0.f) + rac0[j], 0.f);
    y0T[(size_t)((c0 + 1) * NJ0 + j) * R + b] = fmaxf(fmaxf(acc1[j], 0.f) + rac1[j], 0.f);
  }
}

// ---------- K3: h1T = relu(conv1_1 dil2). 2 ch/thread, scalar weights -------
__global__ __launch_bounds__(256) void k3(const float* __restrict__ y0T,
                                          const float* __restrict__ wT11,
                                          const float* __restrict__ b1,
                                          float* __restrict__ h1T) {
  const int id = blockIdx.x;
  const int bblk = id & 63, ct = id >> 6;  // 25 ctiles of 8 -> 200 exact
  const int tid = threadIdx.x;
  const int l = tid & 63, wv = tid >> 6;
  const int b = bblk * 64 + l;
  const int c0 = ct * 8 + __builtin_amdgcn_readfirstlane(wv) * 2;
  float acc0[NT1], acc1[NT1];
  const float bi0 = b1[c0], bi1 = b1[c0 + 1];
#pragma unroll
  for (int t = 0; t < NT1; ++t) { acc0[t] = bi0; acc1[t] = bi1; }
  for (int ci = 0; ci < C1; ++ci) {
    float yr[NJ0];
#pragma unroll
    for (int u = 0; u < NJ0; ++u) yr[u] = y0T[(size_t)(ci * NJ0 + u) * R + b];
#pragma unroll
    for (int k = 0; k < KW; ++k) {
      const float* wr = wT11 + (ci * KW + k) * C2 + c0;
      const float w0 = wr[0], w1v = wr[1];
#pragma unroll
      for (int t = 0; t < NT1; ++t) {
        acc0[t] = fmaf(yr[t + k], w0, acc0[t]);
        acc1[t] = fmaf(yr[t + k], w1v, acc1[t]);
      }
    }
  }
#pragma unroll
  for (int t = 0; t < NT1; ++t) {
    h1T[(size_t)(c0 * NT1 + t) * R + b] = fmaxf(acc0[t], 0.f);
    h1T[(size_t)((c0 + 1) * NT1 + t) * R + b] = fmaxf(acc1[t], 0.f);
  }
}

// ------ K4a: featT = relu(relu(conv2_1@255)+res). GEMM K=1000, scalar w -----
__global__ __launch_bounds__(256) void k4a(const float* __restrict__ h1T,
                                           const float* __restrict__ y0T,
                                           const float* __restrict__ wT21,
                                           const float* __restrict__ b2,
                                           const float* __restrict__ wdT1,
                                           const float* __restrict__ bd,
                                           float* __restrict__ featT) {
  const int id = blockIdx.x;
  const int bblk = id & 63, ct = id >> 6;  // 7 ctiles of 32 ch
  const int tid = threadIdx.x;
  const int l = tid & 63, wv = tid >> 6;
  const int b = bblk * 64 + l;
  int c0 = ct * 32 + __builtin_amdgcn_readfirstlane(wv) * 8;
  c0 = (c0 > C2 - 8) ? C2 - 8 : c0;  // clamp (dup writes identical)
  float acc[8], rs[8];
#pragma unroll
  for (int m = 0; m < 8; ++m) { acc[m] = b2[c0 + m]; rs[m] = bd[c0 + m]; }
#pragma unroll 4
  for (int kk = 0; kk < C2 * KW; ++kk) {
    const float a = h1T[(size_t)kk * R + b];
    const float* wr = wT21 + kk * C2 + c0;  // uniform -> s_load_dwordx8
    acc[0] = fmaf(a, wr[0], acc[0]); acc[1] = fmaf(a, wr[1], acc[1]);
    acc[2] = fmaf(a, wr[2], acc[2]); acc[3] = fmaf(a, wr[3], acc[3]);
    acc[4] = fmaf(a, wr[4], acc[4]); acc[5] = fmaf(a, wr[5], acc[5]);
    acc[6] = fmaf(a, wr[6], acc[6]); acc[7] = fmaf(a, wr[7], acc[7]);
  }
#pragma unroll 4
  for (int ci = 0; ci < C1; ++ci) {
    const float a = y0T[(size_t)(ci * NJ0 + 8) * R + b];
    const float* wr = wdT1 + ci * C2 + c0;
    rs[0] = fmaf(a, wr[0], rs[0]); rs[1] = fmaf(a, wr[1], rs[1]);
    rs[2] = fmaf(a, wr[2], rs[2]); rs[3] = fmaf(a, wr[3], rs[3]);
    rs[4] = fmaf(a, wr[4], rs[4]); rs[5] = fmaf(a, wr[5], rs[5]);
    rs[6] = fmaf(a, wr[6], rs[6]); rs[7] = fmaf(a, wr[7], rs[7]);
  }
#pragma unroll
  for (int m = 0; m < 8; ++m)
    featT[(size_t)(c0 + m) * R + b] = fmaxf(fmaxf(acc[m], 0.f) + rs[m], 0.f);
}

// -------- K4b: per-batch head, transposed W1 (coalesced), wave=item ---------
__global__ __launch_bounds__(256) void k4b(const float* __restrict__ featT,
                                           const int* __restrict__ labels,
                                           const float* __restrict__ hw1T,
                                           const float* __restrict__ hb1,
                                           const float* __restrict__ hw2,
                                           const float* __restrict__ hb2,
                                           float* __restrict__ out) {
  __shared__ float fs[4][C2];
  const int tid = threadIdx.x;
  const int b0 = blockIdx.x * 4;
  for (int idx = tid; idx < 4 * C2; idx += 256) {
    const int c = idx >> 2, bi = idx & 3;
    fs[bi][c] = featT[(size_t)c * R + b0 + bi];
  }
  __syncthreads();
  const int l = tid & 63, wv = tid >> 6;
  const int b = b0 + wv;
  const int task = labels[b];
  const float* Wt = hw1T + (size_t)task * (C1 * C2);  // [d][o]
  const float* fp = fs[wv];
  float a0 = hb1[task * C1 + l];
  float a1 = (l < C1 - 64) ? hb1[task * C1 + 64 + l] : 0.f;
  for (int d = 0; d < C2; ++d) {
    const float fd = fp[d];
    const float* row = Wt + d * C1;
    a0 = fmaf(fd, row[l], a0);
    if (l < C1 - 64) a1 = fmaf(fd, row[64 + l], a1);
  }
  float p = tanhf(a0) * hw2[task * C1 + l];
  if (l < C1 - 64) p = fmaf(tanhf(a1), hw2[task * C1 + 64 + l], p);
#pragma unroll
  for (int off = 32; off > 0; off >>= 1) p += __shfl_down(p, off, 64);
  if (l == 0) out[b] = p + hb2[task];
}

extern "C" void kernel_launch(void* const* d_in, const int* in_sizes, int n_in,
                              void* d_out, int out_size, void* d_ws, size_t ws_size,
                              hipStream_t stream) {
  const float* x    = (const float*)d_in[0];
  const int* labels = (const int*)d_in[1];
  const float* w1_0 = (const float*)d_in[2];
  const float* b1_0 = (const float*)d_in[3];
  const float* w2_0 = (const float*)d_in[4];
  const float* b2_0 = (const float*)d_in[5];
  const float* wd_0 = (const float*)d_in[6];
  const float* bd_0 = (const float*)d_in[7];
  const float* w1_1 = (const float*)d_in[8];
  const float* b1_1 = (const float*)d_in[9];
  const float* w2_1 = (const float*)d_in[10];
  const float* b2_1 = (const float*)d_in[11];
  const float* wd_1 = (const float*)d_in[12];
  const float* bd_1 = (const float*)d_in[13];
  const float* hw1  = (const float*)d_in[14];
  const float* hb1  = (const float*)d_in[15];
  const float* hw2  = (const float*)d_in[16];
  const float* hb2  = (const float*)d_in[17];
  float* out = (float*)d_out;

  float* ws    = (float*)d_ws;
  float* hw1T  = ws + OFF_HW1T;
  float* wT10  = ws + OFF_WT10;
  float* wT20  = ws + OFF_WT20;
  float* wdT0  = ws + OFF_WDT0;
  float* wT11  = ws + OFF_WT11;
  float* wT21  = ws + OFF_WT21;
  float* wdT1  = ws + OFF_WDT1;
  float* xT    = ws + (size_t)ROW_XT * R;
  float* h0T   = ws + (size_t)ROW_H0T * R;
  float* y0T   = ws + (size_t)ROW_Y0T * R;
  float* h1T   = ws + (size_t)ROW_H1T * R;   // aliases xT+h0T head (dead by k3)
  float* featT = ws + (size_t)ROW_FEAT * R;  // inside dead h0T (k4a after k2)

  hipLaunchKernelGGL(k_prep, dim3((NPREP + 255) / 256), dim3(256), 0, stream,
                     hw1, w1_0, w2_0, wd_0, w1_1, w2_1, wd_1, ws);
  hipLaunchKernelGGL(k_tr, dim3(64, 5), dim3(256), 0, stream, x, xT);
  // XCD swizzle: linear id = ct*64 + bblk -> id%8 == bblk%8 (ctiles co-XCD)
  hipLaunchKernelGGL(k1, dim3(13 * 64), dim3(256), 0, stream, xT, wT10, b1_0, h0T);
  hipLaunchKernelGGL(k2, dim3(13 * 64), dim3(256), 0, stream, xT, h0T, wT20, b2_0, wdT0, bd_0, y0T);
  hipLaunchKernelGGL(k3, dim3(25 * 64), dim3(256), 0, stream, y0T, wT11, b1_1, h1T);
  hipLaunchKernelGGL(k4a, dim3(7 * 64), dim3(256), 0, stream, h1T, y0T, wT21, b2_1, wdT1, bd_1, featT);
  hipLaunchKernelGGL(k4b, dim3(1024), dim3(256), 0, stream, featT, labels,
                     hw1T, hb1, hw2, hb2, out);
}